// Round 7
// baseline (797.448 us; speedup 1.0000x reference)
//
#include <hip/hip_runtime.h>
#include <hip/hip_bf16.h>

// Two-table embedding gather + dot product.
//   x:     (16384, 2) indices (harness delivers integer inputs as int32)
//   table: (1500000, 128) float32; user rows = x[:,0], item rows = x[:,1] + 1e6
//   out:   (16384,) float32 = dot(table[x0], table[x1 + 1000000])
//
// Design notes:
//   - Table rows are cache-cold every replay (768MB table > 256MB L3, and the
//     harness restores inputs between launches), so throughput is set by
//     memory-level parallelism, not reuse.
//   - 512B row = 32 lanes x 16B; lanes 0-31 = even row of a pair,
//     lanes 32-63 = odd row -> each vector load gathers 1KB (2 full rows).
//   - Each wave owns 2 row-pairs (4 rows): 4 x 1KB nontemporal gathers in
//     flight before any arithmetic (~4KB/wave; ~64KB/CU at 4 blocks/CU —
//     well above the ~9KB Little's-law bound for 6.3 TB/s).
//   - __builtin_nontemporal_load needs a clang ext_vector_type, not the
//     HIP_vector_type float4 (round-5 compile error, fixed here).
//   - Index pair loaded as one int2 (adjacent in memory).
//   - 5-step __shfl_xor (offsets 16..1) reduces both 32-lane halves
//     simultaneously.

#define BATCH 16384
#define OFFSET_ITEM 1000000
#define ROWS_PER_WAVE 4

typedef float fx4 __attribute__((ext_vector_type(4)));

__global__ __launch_bounds__(256) void emb_dot_kernel(
    const int* __restrict__ x,
    const float* __restrict__ table,
    float* __restrict__ out)
{
    const int wave = (blockIdx.x << 2) | (threadIdx.x >> 6);  // 4 waves/block
    const int lane = threadIdx.x & 63;
    const int half = lane >> 5;       // which row of the pair
    const int sub  = lane & 31;       // 16B slot within the 512B row

    const int row0 = wave * ROWS_PER_WAVE + half;      // pair-0 row
    const int row1 = row0 + 2;                         // pair-1 row

    // One 8B index load per row (adjacent user/item indices).
    const int2 i0 = *(const int2*)(x + row0 * 2);
    const int2 i1 = *(const int2*)(x + row1 * 2);

    // 64-bit row bases (item rows start at float offset 1e6*128 ~ 488MB).
    const fx4* pu0 = (const fx4*)(table + (long long)i0.x * 128) + sub;
    const fx4* pv0 = (const fx4*)(table + ((long long)i0.y + OFFSET_ITEM) * 128) + sub;
    const fx4* pu1 = (const fx4*)(table + (long long)i1.x * 128) + sub;
    const fx4* pv1 = (const fx4*)(table + ((long long)i1.y + OFFSET_ITEM) * 128) + sub;

    // Four independent 1KB gathers in flight before any arithmetic.
    const fx4 a0 = __builtin_nontemporal_load(pu0);
    const fx4 b0 = __builtin_nontemporal_load(pv0);
    const fx4 a1 = __builtin_nontemporal_load(pu1);
    const fx4 b1 = __builtin_nontemporal_load(pv1);

    float s0 = a0.x * b0.x + a0.y * b0.y + a0.z * b0.z + a0.w * b0.w;
    float s1 = a1.x * b1.x + a1.y * b1.y + a1.z * b1.z + a1.w * b1.w;

    // Reduce both 32-lane halves simultaneously (xor offsets <32 stay in-half).
    #pragma unroll
    for (int off = 16; off > 0; off >>= 1) {
        s0 += __shfl_xor(s0, off, 64);
        s1 += __shfl_xor(s1, off, 64);
    }

    if (sub == 0) {
        out[row0] = s0;
        out[row1] = s1;
    }
}

extern "C" void kernel_launch(void* const* d_in, const int* in_sizes, int n_in,
                              void* d_out, int out_size, void* d_ws, size_t ws_size,
                              hipStream_t stream)
{
    const int*   x     = (const int*)d_in[0];
    const float* table = (const float*)d_in[1];
    float*       out   = (float*)d_out;

    const int blocks = BATCH / (ROWS_PER_WAVE * 4);  // 4 waves/block
    emb_dot_kernel<<<blocks, 256, 0, stream>>>(x, table, out);
}